// Round 17
// baseline (189.129 us; speedup 1.0000x reference)
//
#include <hip/hip_runtime.h>
#include <hip/hip_bf16.h>

typedef __attribute__((ext_vector_type(8))) short short8;
typedef __attribute__((ext_vector_type(4))) float f32x4;
typedef __hip_bfloat16 bf16_t;

#define SEQ 2048
#define DM 1024
#define NH 16
#define DK 64
#define NKT 16          // K / 64

static __device__ __forceinline__ f32x4 mfma16x16x32(short8 a, short8 b, f32x4 c) {
  return __builtin_amdgcn_mfma_f32_16x16x32_bf16(a, b, c, 0, 0, 0);
}

// ---- async global->LDS DMA, 16B/lane. LDS dest = wave-uniform base +
// lane*16 (hardware-fixed). Global src is per-lane.
typedef const __attribute__((address_space(1))) unsigned int ga_u32_t;
typedef __attribute__((address_space(3))) unsigned int lds_u32_t;
static __device__ __forceinline__ void gld16(const bf16_t* g, bf16_t* l) {
  __builtin_amdgcn_global_load_lds((ga_u32_t*)g, (lds_u32_t*)l, 16, 0, 0);
}
// raw barrier WITHOUT the vmcnt(0) drain __syncthreads inserts.
static __device__ __forceinline__ void bar() { asm volatile("s_barrier" ::: "memory"); }
static __device__ __forceinline__ void wait_vm8() { asm volatile("s_waitcnt vmcnt(8)" ::: "memory"); }
static __device__ __forceinline__ void wait_vm0() { asm volatile("s_waitcnt vmcnt(0)" ::: "memory"); }

// stage one 128x64 A-tile + 128x64 B-tile into bufbase (A at 0, B at 16KB).
// LDS linear; XOR swizzle lives in the SOURCE column (scg, folded into
// asrc/bsrc) and is inverted on frag reads (rule #21; R14: conflicts 20x down).
static __device__ __forceinline__ void stage_tile(const bf16_t* asrc, const bf16_t* bsrc,
                                                  char* bufbase, int w, int kk) {
#pragma unroll
  for (int j = 0; j < 4; ++j) {
    gld16(asrc + (size_t)(j * 32) * DM + kk, (bf16_t*)(bufbase + j * 4096 + w * 1024));
    gld16(bsrc + (size_t)(j * 32) * DM + kk, (bf16_t*)(bufbase + 16384 + j * 4096 + w * 1024));
  }
}

// ---------------- dtype sniffer: flag=1 if buffers are bf16, 0 if fp32 ------
__global__ void sniff_dtype(const unsigned int* __restrict__ x, int* __restrict__ flag) {
  int lane = threadIdx.x & 63;
  int cnt = 0;
  for (int r = 0; r < 4; ++r) {
    unsigned int v = x[lane + r * 64];
    int e = (v >> 7) & 0xFF;
    if (e >= 100 && e <= 145) cnt++;
  }
  for (int d = 1; d < 64; d <<= 1) cnt += __shfl_xor(cnt, d, 64);
  if (lane == 0) *flag = (cnt >= 192) ? 1 : 0;
}

// ---- merged prep: convert_x | transpose_w | rope table (R12-proven) ----
__global__ __launch_bounds__(256) void prep(const void* __restrict__ x,
                                            bf16_t* __restrict__ Xc,
                                            const void* __restrict__ w0,
                                            const void* __restrict__ w1,
                                            const void* __restrict__ w2,
                                            const void* __restrict__ w3,
                                            bf16_t* __restrict__ wt_base,
                                            const int* __restrict__ tokpos,
                                            float2* __restrict__ rtab,
                                            const int* __restrict__ flag) {
  int f = *flag;
  int bx = blockIdx.x, t = threadIdx.x;
  __shared__ bf16_t tile[64][65];
  if (bx < 4096) {
    int i = bx * 256 + t;
    if (f) {
      ((uint2*)Xc)[i] = ((const uint2*)x)[i];
    } else {
      const float4 v = ((const float4*)x)[i];
      bf16_t o[4] = {__float2bfloat16(v.x), __float2bfloat16(v.y),
                     __float2bfloat16(v.z), __float2bfloat16(v.w)};
      ((uint2*)Xc)[i] = *(const uint2*)o;
    }
  } else if (bx < 5120) {
    int rem = bx - 4096;
    int z = rem >> 8, bxx = rem & 15, byy = (rem >> 4) & 15;
    const void* src = (z == 0) ? w0 : (z == 1) ? w1 : (z == 2) ? w2 : w3;
    bf16_t* dst = wt_base + (size_t)((z + 1) & 3) * DM * DM;
    int tx = t & 63, ty = t >> 6;
    int r0 = byy * 64, c0 = bxx * 64;
    for (int i = 0; i < 64; i += 4) {
      size_t idx = (size_t)(r0 + ty + i) * DM + c0 + tx;
      tile[ty + i][tx] = f ? ((const bf16_t*)src)[idx]
                           : __float2bfloat16(((const float*)src)[idx]);
    }
    __syncthreads();
    for (int i = 0; i < 64; i += 4)
      dst[(size_t)(c0 + ty + i) * DM + r0 + tx] = tile[tx][ty + i];
  } else {
    int i = (bx - 5120) * 256 + t;    // i = m*32 + p
    int m = i >> 5, pp = i & 31;
    float pos = (float)tokpos[m];
    float invf = __powf(10000.0f, -(float)pp * (1.0f / 32.0f));
    float sn, cs;
    sincosf(pos * invf, &sn, &cs);
    rtab[i] = make_float2(cs, sn);
  }
}

// ------ fused QKV GEMM + RoPE(table), 128x128, 2-buf counted-vmcnt --------
// (R16-proven: total 185.8us best; structure unchanged this round)
__global__ __launch_bounds__(256) void gemm128_qkv(const bf16_t* __restrict__ A,
                                                   const bf16_t* __restrict__ WTqkv,
                                                   bf16_t* __restrict__ Qb,
                                                   bf16_t* __restrict__ Kb,
                                                   bf16_t* __restrict__ VTo,
                                                   const float2* __restrict__ rtab) {
  __shared__ __align__(16) char smem[65536];        // 2 x 32KB buffers
  int t = threadIdx.x;
  int w = t >> 6, lane = t & 63, l15 = lane & 15, quad = lane >> 4;
  int wrow = w >> 1, wcol = w & 1;
  int m0 = blockIdx.y * 128, nx = blockIdx.x, n0 = nx * 128;
  int srow0 = w * 8 + (lane >> 3);
  int scg = (lane & 7) ^ (lane >> 3);
  const bf16_t* asrc = A + (size_t)(m0 + srow0) * DM + scg * 8;
  const bf16_t* bsrc = WTqkv + (size_t)(n0 + srow0) * DM + scg * 8;

  f32x4 acc[4][4] = {};
  stage_tile(asrc, bsrc, smem, w, 0);
  stage_tile(asrc, bsrc, smem + 32768, w, 64);
  for (int kt = 0; kt < NKT; ++kt) {
    if (kt < NKT - 1) wait_vm8(); else wait_vm0();
    bar();
    const bf16_t* Ab = (const bf16_t*)(smem + (kt & 1) * 32768);
    const bf16_t* Bb = Ab + 8192;
    short8 af[4][2], bfr[4][2];
#pragma unroll
    for (int mt = 0; mt < 4; ++mt) {
      int r = wrow * 64 + mt * 16 + l15;
      af[mt][0] = *(const short8*)(Ab + r * 64 + ((quad ^ (l15 & 7)) * 8));
      af[mt][1] = *(const short8*)(Ab + r * 64 + (((4 + quad) ^ (l15 & 7)) * 8));
    }
#pragma unroll
    for (int nt = 0; nt < 4; ++nt) {
      int r = wcol * 64 + nt * 16 + l15;
      bfr[nt][0] = *(const short8*)(Bb + r * 64 + ((quad ^ (l15 & 7)) * 8));
      bfr[nt][1] = *(const short8*)(Bb + r * 64 + (((4 + quad) ^ (l15 & 7)) * 8));
    }
#pragma unroll
    for (int mt = 0; mt < 4; ++mt)
#pragma unroll
      for (int nt = 0; nt < 4; ++nt) {
        acc[mt][nt] = mfma16x16x32(af[mt][0], bfr[nt][0], acc[mt][nt]);
        acc[mt][nt] = mfma16x16x32(af[mt][1], bfr[nt][1], acc[mt][nt]);
      }
    bar();                                           // reads of buf[kt&1] done
    if (kt + 2 < NKT)
      stage_tile(asrc, bsrc, smem + (kt & 1) * 32768, w, (kt + 2) * 64);
  }

  int sel = nx >> 3;                 // 0=Q, 1=K, 2=V
  int nc = (nx & 7) * 128;
  __syncthreads();                   // buffers dead; carve Tw
  bf16_t (*Tw)[72] = (bf16_t(*)[72])(smem + w * 9216);  // per-wave 64x72
  int b = m0 >> 11;
  int h = (nc >> 6) + wcol;
  if (sel < 2) {
    bf16_t* dst = sel ? Kb : Qb;
    float sgnv = (l15 & 1) ? 1.0f : -1.0f;
#pragma unroll
    for (int mt = 0; mt < 4; ++mt)
#pragma unroll
      for (int r = 0; r < 4; ++r) {
        int m = m0 + wrow * 64 + mt * 16 + quad * 4 + r;
        const float2* tr = rtab + m * 32;
#pragma unroll
        for (int nt = 0; nt < 4; ++nt) {
          int d = nt * 16 + l15;
          float val = acc[mt][nt][r];
          float partner = __shfl_xor(val, 1, 64);
          float2 cssn = tr[d >> 1];
          Tw[mt * 16 + quad * 4 + r][d] = __float2bfloat16(val * cssn.x + sgnv * partner * cssn.y);
        }
      }
    int s_base = (m0 & (SEQ - 1)) + wrow * 64;
    bf16_t* dq = dst + ((size_t)(b * NH + h) * SEQ + s_base) * DK;
#pragma unroll
    for (int c = 0; c < 8; ++c) {
      int row = c * 8 + (lane >> 3);
      int col = (lane & 7) * 8;
      *(short8*)&dq[(size_t)row * DK + col] = *(const short8*)&Tw[row][col];
    }
  } else {
#pragma unroll
    for (int mt = 0; mt < 4; ++mt)
#pragma unroll
      for (int nt = 0; nt < 4; ++nt)
#pragma unroll
        for (int r = 0; r < 4; ++r)
          Tw[nt * 16 + l15][mt * 16 + quad * 4 + r] = __float2bfloat16(acc[mt][nt][r]);
    int s_base = m0 & (SEQ - 1);
#pragma unroll
    for (int c = 0; c < 4; ++c) {
      int d = c * 16 + (lane >> 2);
      int s2 = (lane & 3) * 16;
      size_t ob = ((size_t)(b * NH + h) * DK + d) * SEQ + s_base + wrow * 64 + s2;
      *(short8*)&VTo[ob] = *(const short8*)&Tw[d][s2];
      *(short8*)&VTo[ob + 8] = *(const short8*)&Tw[d][s2 + 8];
    }
  }
}

// ------ out-proj GEMM, same 2-buf counted-vmcnt pipeline (R16-proven) ------
__global__ __launch_bounds__(256) void gemm128_out(const bf16_t* __restrict__ A,
                                                   const bf16_t* __restrict__ BT,
                                                   void* __restrict__ out,
                                                   const int* __restrict__ flag) {
  __shared__ __align__(16) char smem[65536];
  int f = *flag;
  int t = threadIdx.x;
  int w = t >> 6, lane = t & 63, l15 = lane & 15, quad = lane >> 4;
  int wrow = w >> 1, wcol = w & 1;
  int m0 = blockIdx.y * 128, n0 = blockIdx.x * 128;
  int srow0 = w * 8 + (lane >> 3);
  int scg = (lane & 7) ^ (lane >> 3);
  const bf16_t* asrc = A + (size_t)(m0 + srow0) * DM + scg * 8;
  const bf16_t* bsrc = BT + (size_t)(n0 + srow0) * DM + scg * 8;

  f32x4 acc[4][4] = {};
  stage_tile(asrc, bsrc, smem, w, 0);
  stage_tile(asrc, bsrc, smem + 32768, w, 64);
  for (int kt = 0; kt < NKT; ++kt) {
    if (kt < NKT - 1) wait_vm8(); else wait_vm0();
    bar();
    const bf16_t* Ab = (const bf16_t*)(smem + (kt & 1) * 32768);
    const bf16_t* Bb = Ab + 8192;
    short8 af[4][2], bfr[4][2];
#pragma unroll
    for (int mt = 0; mt < 4; ++mt) {
      int r = wrow * 64 + mt * 16 + l15;
      af[mt][0] = *(const short8*)(Ab + r * 64 + ((quad ^ (l15 & 7)) * 8));
      af[mt][1] = *(const short8*)(Ab + r * 64 + (((4 + quad) ^ (l15 & 7)) * 8));
    }
#pragma unroll
    for (int nt = 0; nt < 4; ++nt) {
      int r = wcol * 64 + nt * 16 + l15;
      bfr[nt][0] = *(const short8*)(Bb + r * 64 + ((quad ^ (l15 & 7)) * 8));
      bfr[nt][1] = *(const short8*)(Bb + r * 64 + (((4 + quad) ^ (l15 & 7)) * 8));
    }
#pragma unroll
    for (int mt = 0; mt < 4; ++mt)
#pragma unroll
      for (int nt = 0; nt < 4; ++nt) {
        acc[mt][nt] = mfma16x16x32(af[mt][0], bfr[nt][0], acc[mt][nt]);
        acc[mt][nt] = mfma16x16x32(af[mt][1], bfr[nt][1], acc[mt][nt]);
      }
    bar();
    if (kt + 2 < NKT)
      stage_tile(asrc, bsrc, smem + (kt & 1) * 32768, w, (kt + 2) * 64);
  }
#pragma unroll
  for (int mt = 0; mt < 4; ++mt)
#pragma unroll
    for (int nt = 0; nt < 4; ++nt)
#pragma unroll
      for (int r = 0; r < 4; ++r) {
        int m = m0 + wrow * 64 + mt * 16 + quad * 4 + r;
        int col = n0 + wcol * 64 + nt * 16 + l15;
        size_t oidx = (size_t)m * DM + col;
        if (f) ((bf16_t*)out)[oidx] = __float2bfloat16(acc[mt][nt][r]);
        else   ((float*)out)[oidx] = acc[mt][nt][r];
      }
}

// -- causal flash attention: DUAL-Q, 8 waves / 512 threads, kv-parity split.
// R16: 17% occupancy (512 blocks x 4 waves = 2/SIMD) was the limiter.
// Wave-group g in {0,1} sweeps kv tiles kb==g (mod 2) into its OWN Ks/Vs
// buffers (staging total unchanged), accumulating private (O,r) partials;
// fixed-max softmax => partials are plain sums, combined once via LDS at
// the end. 512 blocks x 8 waves = 4/SIMD. LDS 72KB -> 2 blocks/CU.
// Plain __launch_bounds__(512): NO second arg (R1/R2 spill lesson).
__global__ __launch_bounds__(512) void attn_fwd(const bf16_t* __restrict__ Q,
                                                const bf16_t* __restrict__ K,
                                                const bf16_t* __restrict__ VT,
                                                bf16_t* __restrict__ O) {
  int x = blockIdx.x, bh = blockIdx.y;
  int b = bh >> 4, h = bh & 15;
  int g4 = x + (bh << 4);                   // linear block id (gridDim.x=16)
  int raw = (g4 + (g4 >> 8)) & 15;
  const int pmap[16] = {0, 15, 1, 13, 2, 12, 3, 11, 4, 10, 5, 9, 6, 8, 7, 14};
  int p = pmap[raw];
  int qA = p, qB = 31 - p;                  // qA<16<=qB
  int t = threadIdx.x;
  int w = t >> 6, lane = t & 63, l15 = lane & 15, quad = lane >> 4;
  int g = w >> 2;                           // kv-parity group
  int wq = w & 3;                           // row-quad within 64-row tile
  const size_t base = (size_t)bh * SEQ * DK;
  const bf16_t* Qp = Q + base;
  const bf16_t* Kp = K + base;
  const bf16_t* VTp = VT + base;            // [DK][SEQ]

  __shared__ __align__(16) char smem[73728];
  bf16_t (*Ks)[64][72] = (bf16_t(*)[64][72])smem;             // [2] per-group K
  bf16_t (*Vs)[64][72] = (bf16_t(*)[64][72])(smem + 18432);   // [2] per-group V^T
  bf16_t (*Pb)[2][16][72] = (bf16_t(*)[2][16][72])(smem + 36864); // [8] per-wave P

  int rowA = qA * 64 + wq * 16 + l15;
  int rowB = qB * 64 + wq * 16 + l15;
  short8 qfA0 = *(const short8*)(Qp + (size_t)rowA * DK + quad * 8);
  short8 qfA1 = *(const short8*)(Qp + (size_t)rowA * DK + 32 + quad * 8);
  short8 qfB0 = *(const short8*)(Qp + (size_t)rowB * DK + quad * 8);
  short8 qfB1 = *(const short8*)(Qp + (size_t)rowB * DK + 32 + quad * 8);

  int tl = t & 255;                                  // thread id within group
  int srow = tl >> 2, scoff = (tl & 3) * 16;         // staging layout
  const bf16_t* kst = Kp + (size_t)srow * DK + scoff;
  const bf16_t* vst = VTp + (size_t)srow * SEQ + scoff;

  // prologue: group g loads tile kb=g (qB>=16 so both exist)
  short8 kA = *(const short8*)(kst + (size_t)g * 64 * DK);
  short8 kB = *(const short8*)(kst + (size_t)g * 64 * DK + 8);
  short8 vA = *(const short8*)(vst + (size_t)g * 64);
  short8 vB = *(const short8*)(vst + (size_t)g * 64 + 8);

  f32x4 oA[4] = {}, oB[4] = {};
  float rA[4] = {0.f, 0.f, 0.f, 0.f}, rB[4] = {0.f, 0.f, 0.f, 0.f};

  int ni = qB / 2 + 1;                               // max iters over groups
  for (int i = 0; i < ni; ++i) {
    int kb = 2 * i + g;
    bool active = (kb <= qB);
    __syncthreads();
    if (active) {
      *(short8*)&Ks[g][srow][scoff] = kA;
      *(short8*)&Ks[g][srow][scoff + 8] = kB;
      *(short8*)&Vs[g][srow][scoff] = vA;
      *(short8*)&Vs[g][srow][scoff + 8] = vB;
    }
    __syncthreads();

    int nkb = (kb + 2 <= qB) ? (kb + 2) : kb;        // clamp (harmless reload)
    if (active) {
      kA = *(const short8*)(kst + (size_t)nkb * 64 * DK);
      kB = *(const short8*)(kst + (size_t)nkb * 64 * DK + 8);
      vA = *(const short8*)(vst + (size_t)nkb * 64);
      vB = *(const short8*)(vst + (size_t)nkb * 64 + 8);
    }
    if (!active) continue;                           // barriers already hit

    bool doA = (kb <= qA);
    // ---- B: QK^T -> softmax-partial -> PV ----
    {
      f32x4 sc[4];
#pragma unroll
      for (int kt = 0; kt < 4; ++kt) {
        f32x4 a = {};
        a = mfma16x16x32(qfB0, *(const short8*)&Ks[g][kt * 16 + l15][quad * 8], a);
        a = mfma16x16x32(qfB1, *(const short8*)&Ks[g][kt * 16 + l15][32 + quad * 8], a);
        sc[kt] = a;
      }
      bool diag = (kb == qB);
#pragma unroll
      for (int kt = 0; kt < 4; ++kt)
#pragma unroll
        for (int reg = 0; reg < 4; ++reg) {
          float sv = sc[kt][reg] * 0.125f;
          if (diag) {
            int kg = kt * 16 + l15, qg = wq * 16 + quad * 4 + reg;
            if (kg > qg) sv = -30000.0f;   // exp underflows to exactly 0
          }
          float pp = __expf(sv);
          rB[reg] += pp;
          Pb[w][1][quad * 4 + reg][kt * 16 + l15] = __float2bfloat16(pp);
        }
      short8 p0 = *(const short8*)&Pb[w][1][l15][quad * 8];
      short8 p1 = *(const short8*)&Pb[w][1][l15][32 + quad * 8];
#pragma unroll
      for (int dt = 0; dt < 4; ++dt) {
        oB[dt] = mfma16x16x32(p0, *(const short8*)&Vs[g][dt * 16 + l15][quad * 8], oB[dt]);
        oB[dt] = mfma16x16x32(p1, *(const short8*)&Vs[g][dt * 16 + l15][32 + quad * 8], oB[dt]);
      }
    }
    // ---- A (only while kb <= qA; group/wave-uniform branch) ----
    if (doA) {
      f32x4 sc[4];
#pragma unroll
      for (int kt = 0; kt < 4; ++kt) {
        f32x4 a = {};
        a = mfma16x16x32(qfA0, *(const short8*)&Ks[g][kt * 16 + l15][quad * 8], a);
        a = mfma16x16x32(qfA1, *(const short8*)&Ks[g][kt * 16 + l15][32 + quad * 8], a);
        sc[kt] = a;
      }
      bool diag = (kb == qA);
#pragma unroll
      for (int kt = 0; kt < 4; ++kt)
#pragma unroll
        for (int reg = 0; reg < 4; ++reg) {
          float sv = sc[kt][reg] * 0.125f;
          if (diag) {
            int kg = kt * 16 + l15, qg = wq * 16 + quad * 4 + reg;
            if (kg > qg) sv = -30000.0f;
          }
          float pp = __expf(sv);
          rA[reg] += pp;
          Pb[w][0][quad * 4 + reg][kt * 16 + l15] = __float2bfloat16(pp);
        }
      short8 p0 = *(const short8*)&Pb[w][0][l15][quad * 8];
      short8 p1 = *(const short8*)&Pb[w][0][l15][32 + quad * 8];
#pragma unroll
      for (int dt = 0; dt < 4; ++dt) {
        oA[dt] = mfma16x16x32(p0, *(const short8*)&Vs[g][dt * 16 + l15][quad * 8], oA[dt]);
        oA[dt] = mfma16x16x32(p1, *(const short8*)&Vs[g][dt * 16 + l15][32 + quad * 8], oA[dt]);
      }
    }
  }

  // per-group deferred row-sum reduce (across l15 within each quad)
  for (int d = 1; d < 16; d <<= 1)
#pragma unroll
    for (int reg = 0; reg < 4; ++reg) {
      rA[reg] += __shfl_xor(rA[reg], d, 64);
      rB[reg] += __shfl_xor(rB[reg], d, 64);
    }

  // ---- combine the two kv-parity groups via LDS (A and B together) ----
  // Overlay on dead Ks/Vs region: OcA/OcB [4][16][68] f32 + RcA/RcB [4][16].
  float (*OcA)[16][68] = (float(*)[16][68])smem;
  float (*OcB)[16][68] = (float(*)[16][68])(smem + 17408);
  float (*RcA)[16] = (float(*)[16])(smem + 34816);
  float (*RcB)[16] = (float(*)[16])(smem + 35072);
  __syncthreads();
  if (g == 1) {
#pragma unroll
    for (int dt = 0; dt < 4; ++dt)
#pragma unroll
      for (int reg = 0; reg < 4; ++reg) {
        OcA[wq][quad * 4 + reg][dt * 16 + l15] = oA[dt][reg];
        OcB[wq][quad * 4 + reg][dt * 16 + l15] = oB[dt][reg];
      }
    if (l15 == 0)
#pragma unroll
      for (int reg = 0; reg < 4; ++reg) {
        RcA[wq][quad * 4 + reg] = rA[reg];
        RcB[wq][quad * 4 + reg] = rB[reg];
      }
  }
  __syncthreads();
  if (g == 0) {
#pragma unroll
    for (int dt = 0; dt < 4; ++dt)
#pragma unroll
      for (int reg = 0; reg < 4; ++reg) {
        oA[dt][reg] += OcA[wq][quad * 4 + reg][dt * 16 + l15];
        oB[dt][reg] += OcB[wq][quad * 4 + reg][dt * 16 + l15];
      }
#pragma unroll
    for (int reg = 0; reg < 4; ++reg) {
      rA[reg] += RcA[wq][quad * 4 + reg];
      rB[reg] += RcB[wq][quad * 4 + reg];
    }
#pragma unroll
    for (int dt = 0; dt < 4; ++dt)
#pragma unroll
      for (int reg = 0; reg < 4; ++reg) {
        int col = h * DK + dt * 16 + l15;
        int qa = qA * 64 + wq * 16 + quad * 4 + reg;
        int qb_ = qB * 64 + wq * 16 + quad * 4 + reg;
        O[((size_t)b * SEQ + qa) * DM + col] = __float2bfloat16(oA[dt][reg] / rA[reg]);
        O[((size_t)b * SEQ + qb_) * DM + col] = __float2bfloat16(oB[dt][reg] / rB[reg]);
      }
  }
}

extern "C" void kernel_launch(void* const* d_in, const int* in_sizes, int n_in,
                              void* d_out, int out_size, void* d_ws, size_t ws_size,
                              hipStream_t stream) {
  const void* x = d_in[0];
  const int* tokpos = (const int*)d_in[1];
  const void* WQ = d_in[2];
  const void* WK = d_in[3];
  const void* WV = d_in[4];
  const void* WO = d_in[5];

  char* ws = (char*)d_ws;
  const size_t MB = 1024 * 1024;
  bf16_t* WT  = (bf16_t*)ws;              // 0-8 MB: slot0=WO, slots1-3=WQ,WK,WV
  bf16_t* Xc  = (bf16_t*)(ws + 8 * MB);   // 8-16: x bf16 (dead after gemm_qkv)
  bf16_t* Qb  = (bf16_t*)(ws + 16 * MB);  // 16-24: Q roped [b,h,s,d]
  bf16_t* Kb  = (bf16_t*)(ws + 24 * MB);  // 24-32: K roped [b,h,s,d]
  bf16_t* VTb = (bf16_t*)(ws + 32 * MB);  // 32-40: V^T [b,h,d,s]
  bf16_t* Ab  = (bf16_t*)(ws + 8 * MB);   // overlays dead Xc after gemm_qkv
  int* flag   = (int*)(ws + 40 * MB);
  float2* rtab = (float2*)(ws + 41 * MB); // 41-42: rope cos/sin table (1MB)

  dim3 blk(256);
  dim3 blk512(512);
  sniff_dtype<<<1, 64, 0, stream>>>((const unsigned int*)x, flag);
  prep<<<5632, blk, 0, stream>>>(x, Xc, WQ, WK, WV, WO, WT, tokpos, rtab, flag);
  gemm128_qkv<<<dim3(24, 32), blk, 0, stream>>>(Xc, WT + (size_t)DM * DM, Qb, Kb, VTb, rtab);
  attn_fwd<<<dim3(16, 32), blk512, 0, stream>>>(Qb, Kb, VTb, Ab);
  gemm128_out<<<dim3(8, 32), blk, 0, stream>>>(Ab, WT, d_out, flag);
}

// Round 18
// 186.252 us; speedup vs baseline: 1.0154x; 1.0154x over previous
//
#include <hip/hip_runtime.h>
#include <hip/hip_bf16.h>

typedef __attribute__((ext_vector_type(8))) short short8;
typedef __attribute__((ext_vector_type(4))) float f32x4;
typedef __hip_bfloat16 bf16_t;

#define SEQ 2048
#define DM 1024
#define NH 16
#define DK 64
#define NKT 16          // K / 64

static __device__ __forceinline__ f32x4 mfma16x16x32(short8 a, short8 b, f32x4 c) {
  return __builtin_amdgcn_mfma_f32_16x16x32_bf16(a, b, c, 0, 0, 0);
}

// ---- async global->LDS DMA, 16B/lane. LDS dest = wave-uniform base +
// lane*16 (hardware-fixed). Global src is per-lane.
typedef const __attribute__((address_space(1))) unsigned int ga_u32_t;
typedef __attribute__((address_space(3))) unsigned int lds_u32_t;
static __device__ __forceinline__ void gld16(const bf16_t* g, bf16_t* l) {
  __builtin_amdgcn_global_load_lds((ga_u32_t*)g, (lds_u32_t*)l, 16, 0, 0);
}
// raw barrier WITHOUT the vmcnt(0) drain __syncthreads inserts.
static __device__ __forceinline__ void bar() { asm volatile("s_barrier" ::: "memory"); }
static __device__ __forceinline__ void wait_vm8() { asm volatile("s_waitcnt vmcnt(8)" ::: "memory"); }
static __device__ __forceinline__ void wait_vm0() { asm volatile("s_waitcnt vmcnt(0)" ::: "memory"); }

// stage one 128x64 A-tile + 128x64 B-tile into bufbase (A at 0, B at 16KB).
// LDS linear; XOR swizzle lives in the SOURCE column (scg, folded into
// asrc/bsrc) and is inverted on frag reads (rule #21; R14: conflicts 20x down).
static __device__ __forceinline__ void stage_tile(const bf16_t* asrc, const bf16_t* bsrc,
                                                  char* bufbase, int w, int kk) {
#pragma unroll
  for (int j = 0; j < 4; ++j) {
    gld16(asrc + (size_t)(j * 32) * DM + kk, (bf16_t*)(bufbase + j * 4096 + w * 1024));
    gld16(bsrc + (size_t)(j * 32) * DM + kk, (bf16_t*)(bufbase + 16384 + j * 4096 + w * 1024));
  }
}

// ---- merged prep: per-block dtype sniff (deterministic, replaces the
// separate sniff kernel + launch gap) | convert_x (blocks 0..4095) |
// transpose_w (4096..5119) | rope table (5120..5631). Trig lives here
// (tiny live set — R7 lesson: sincosf in the gemm epilogue spilled acc).
__global__ __launch_bounds__(256) void prep(const void* __restrict__ x,
                                            bf16_t* __restrict__ Xc,
                                            const void* __restrict__ w0,
                                            const void* __restrict__ w1,
                                            const void* __restrict__ w2,
                                            const void* __restrict__ w3,
                                            bf16_t* __restrict__ wt_base,
                                            const int* __restrict__ tokpos,
                                            float2* __restrict__ rtab,
                                            int* __restrict__ flag) {
  __shared__ int flg;
  __shared__ bf16_t tile[64][65];
  int bx = blockIdx.x, t = threadIdx.x;
  if (t < 64) {
    int lane = t;
    int cnt = 0;
    for (int r = 0; r < 4; ++r) {
      unsigned int v = ((const unsigned int*)x)[lane + r * 64];
      int e = (v >> 7) & 0xFF;
      if (e >= 100 && e <= 145) cnt++;
    }
    for (int d = 1; d < 64; d <<= 1) cnt += __shfl_xor(cnt, d, 64);
    if (lane == 0) flg = (cnt >= 192) ? 1 : 0;
  }
  __syncthreads();
  int f = flg;
  if (bx == 0 && t == 0) *flag = f;    // for gemm128_out's output dtype
  if (bx < 4096) {
    int i = bx * 256 + t;
    if (f) {
      ((uint2*)Xc)[i] = ((const uint2*)x)[i];
    } else {
      const float4 v = ((const float4*)x)[i];
      bf16_t o[4] = {__float2bfloat16(v.x), __float2bfloat16(v.y),
                     __float2bfloat16(v.z), __float2bfloat16(v.w)};
      ((uint2*)Xc)[i] = *(const uint2*)o;
    }
  } else if (bx < 5120) {
    int rem = bx - 4096;
    int z = rem >> 8, bxx = rem & 15, byy = (rem >> 4) & 15;
    const void* src = (z == 0) ? w0 : (z == 1) ? w1 : (z == 2) ? w2 : w3;
    bf16_t* dst = wt_base + (size_t)((z + 1) & 3) * DM * DM;
    int tx = t & 63, ty = t >> 6;
    int r0 = byy * 64, c0 = bxx * 64;
    for (int i = 0; i < 64; i += 4) {
      size_t idx = (size_t)(r0 + ty + i) * DM + c0 + tx;
      tile[ty + i][tx] = f ? ((const bf16_t*)src)[idx]
                           : __float2bfloat16(((const float*)src)[idx]);
    }
    __syncthreads();
    for (int i = 0; i < 64; i += 4)
      dst[(size_t)(c0 + ty + i) * DM + r0 + tx] = tile[tx][ty + i];
  } else {
    int i = (bx - 5120) * 256 + t;    // i = m*32 + p
    int m = i >> 5, pp = i & 31;
    float pos = (float)tokpos[m];
    float invf = __powf(10000.0f, -(float)pp * (1.0f / 32.0f));
    float sn, cs;
    sincosf(pos * invf, &sn, &cs);
    rtab[i] = make_float2(cs, sn);
  }
}

// ------ fused QKV GEMM + RoPE(table), 128x128, 2-buf counted-vmcnt --------
// (R16-proven: structure unchanged)
__global__ __launch_bounds__(256) void gemm128_qkv(const bf16_t* __restrict__ A,
                                                   const bf16_t* __restrict__ WTqkv,
                                                   bf16_t* __restrict__ Qb,
                                                   bf16_t* __restrict__ Kb,
                                                   bf16_t* __restrict__ VTo,
                                                   const float2* __restrict__ rtab) {
  __shared__ __align__(16) char smem[65536];        // 2 x 32KB buffers
  int t = threadIdx.x;
  int w = t >> 6, lane = t & 63, l15 = lane & 15, quad = lane >> 4;
  int wrow = w >> 1, wcol = w & 1;
  int m0 = blockIdx.y * 128, nx = blockIdx.x, n0 = nx * 128;
  int srow0 = w * 8 + (lane >> 3);
  int scg = (lane & 7) ^ (lane >> 3);
  const bf16_t* asrc = A + (size_t)(m0 + srow0) * DM + scg * 8;
  const bf16_t* bsrc = WTqkv + (size_t)(n0 + srow0) * DM + scg * 8;

  f32x4 acc[4][4] = {};
  stage_tile(asrc, bsrc, smem, w, 0);
  stage_tile(asrc, bsrc, smem + 32768, w, 64);
  for (int kt = 0; kt < NKT; ++kt) {
    if (kt < NKT - 1) wait_vm8(); else wait_vm0();
    bar();
    const bf16_t* Ab = (const bf16_t*)(smem + (kt & 1) * 32768);
    const bf16_t* Bb = Ab + 8192;
    short8 af[4][2], bfr[4][2];
#pragma unroll
    for (int mt = 0; mt < 4; ++mt) {
      int r = wrow * 64 + mt * 16 + l15;
      af[mt][0] = *(const short8*)(Ab + r * 64 + ((quad ^ (l15 & 7)) * 8));
      af[mt][1] = *(const short8*)(Ab + r * 64 + (((4 + quad) ^ (l15 & 7)) * 8));
    }
#pragma unroll
    for (int nt = 0; nt < 4; ++nt) {
      int r = wcol * 64 + nt * 16 + l15;
      bfr[nt][0] = *(const short8*)(Bb + r * 64 + ((quad ^ (l15 & 7)) * 8));
      bfr[nt][1] = *(const short8*)(Bb + r * 64 + (((4 + quad) ^ (l15 & 7)) * 8));
    }
#pragma unroll
    for (int mt = 0; mt < 4; ++mt)
#pragma unroll
      for (int nt = 0; nt < 4; ++nt) {
        acc[mt][nt] = mfma16x16x32(af[mt][0], bfr[nt][0], acc[mt][nt]);
        acc[mt][nt] = mfma16x16x32(af[mt][1], bfr[nt][1], acc[mt][nt]);
      }
    bar();                                           // reads of buf[kt&1] done
    if (kt + 2 < NKT)
      stage_tile(asrc, bsrc, smem + (kt & 1) * 32768, w, (kt + 2) * 64);
  }

  int sel = nx >> 3;                 // 0=Q, 1=K, 2=V
  int nc = (nx & 7) * 128;
  __syncthreads();                   // buffers dead; carve Tw
  bf16_t (*Tw)[72] = (bf16_t(*)[72])(smem + w * 9216);  // per-wave 64x72
  int b = m0 >> 11;
  int h = (nc >> 6) + wcol;
  if (sel < 2) {
    bf16_t* dst = sel ? Kb : Qb;
    float sgnv = (l15 & 1) ? 1.0f : -1.0f;
#pragma unroll
    for (int mt = 0; mt < 4; ++mt)
#pragma unroll
      for (int r = 0; r < 4; ++r) {
        int m = m0 + wrow * 64 + mt * 16 + quad * 4 + r;
        const float2* tr = rtab + m * 32;
#pragma unroll
        for (int nt = 0; nt < 4; ++nt) {
          int d = nt * 16 + l15;
          float val = acc[mt][nt][r];
          float partner = __shfl_xor(val, 1, 64);
          float2 cssn = tr[d >> 1];
          Tw[mt * 16 + quad * 4 + r][d] = __float2bfloat16(val * cssn.x + sgnv * partner * cssn.y);
        }
      }
    int s_base = (m0 & (SEQ - 1)) + wrow * 64;
    bf16_t* dq = dst + ((size_t)(b * NH + h) * SEQ + s_base) * DK;
#pragma unroll
    for (int c = 0; c < 8; ++c) {
      int row = c * 8 + (lane >> 3);
      int col = (lane & 7) * 8;
      *(short8*)&dq[(size_t)row * DK + col] = *(const short8*)&Tw[row][col];
    }
  } else {
#pragma unroll
    for (int mt = 0; mt < 4; ++mt)
#pragma unroll
      for (int nt = 0; nt < 4; ++nt)
#pragma unroll
        for (int r = 0; r < 4; ++r)
          Tw[nt * 16 + l15][mt * 16 + quad * 4 + r] = __float2bfloat16(acc[mt][nt][r]);
    int s_base = m0 & (SEQ - 1);
#pragma unroll
    for (int c = 0; c < 4; ++c) {
      int d = c * 16 + (lane >> 2);
      int s2 = (lane & 3) * 16;
      size_t ob = ((size_t)(b * NH + h) * DK + d) * SEQ + s_base + wrow * 64 + s2;
      *(short8*)&VTo[ob] = *(const short8*)&Tw[d][s2];
      *(short8*)&VTo[ob + 8] = *(const short8*)&Tw[d][s2 + 8];
    }
  }
}

// ------ out-proj GEMM, same 2-buf counted-vmcnt pipeline (R16-proven) ------
__global__ __launch_bounds__(256) void gemm128_out(const bf16_t* __restrict__ A,
                                                   const bf16_t* __restrict__ BT,
                                                   void* __restrict__ out,
                                                   const int* __restrict__ flag) {
  __shared__ __align__(16) char smem[65536];
  int f = *flag;
  int t = threadIdx.x;
  int w = t >> 6, lane = t & 63, l15 = lane & 15, quad = lane >> 4;
  int wrow = w >> 1, wcol = w & 1;
  int m0 = blockIdx.y * 128, n0 = blockIdx.x * 128;
  int srow0 = w * 8 + (lane >> 3);
  int scg = (lane & 7) ^ (lane >> 3);
  const bf16_t* asrc = A + (size_t)(m0 + srow0) * DM + scg * 8;
  const bf16_t* bsrc = BT + (size_t)(n0 + srow0) * DM + scg * 8;

  f32x4 acc[4][4] = {};
  stage_tile(asrc, bsrc, smem, w, 0);
  stage_tile(asrc, bsrc, smem + 32768, w, 64);
  for (int kt = 0; kt < NKT; ++kt) {
    if (kt < NKT - 1) wait_vm8(); else wait_vm0();
    bar();
    const bf16_t* Ab = (const bf16_t*)(smem + (kt & 1) * 32768);
    const bf16_t* Bb = Ab + 8192;
    short8 af[4][2], bfr[4][2];
#pragma unroll
    for (int mt = 0; mt < 4; ++mt) {
      int r = wrow * 64 + mt * 16 + l15;
      af[mt][0] = *(const short8*)(Ab + r * 64 + ((quad ^ (l15 & 7)) * 8));
      af[mt][1] = *(const short8*)(Ab + r * 64 + (((4 + quad) ^ (l15 & 7)) * 8));
    }
#pragma unroll
    for (int nt = 0; nt < 4; ++nt) {
      int r = wcol * 64 + nt * 16 + l15;
      bfr[nt][0] = *(const short8*)(Bb + r * 64 + ((quad ^ (l15 & 7)) * 8));
      bfr[nt][1] = *(const short8*)(Bb + r * 64 + (((4 + quad) ^ (l15 & 7)) * 8));
    }
#pragma unroll
    for (int mt = 0; mt < 4; ++mt)
#pragma unroll
      for (int nt = 0; nt < 4; ++nt) {
        acc[mt][nt] = mfma16x16x32(af[mt][0], bfr[nt][0], acc[mt][nt]);
        acc[mt][nt] = mfma16x16x32(af[mt][1], bfr[nt][1], acc[mt][nt]);
      }
    bar();
    if (kt + 2 < NKT)
      stage_tile(asrc, bsrc, smem + (kt & 1) * 32768, w, (kt + 2) * 64);
  }
#pragma unroll
  for (int mt = 0; mt < 4; ++mt)
#pragma unroll
    for (int nt = 0; nt < 4; ++nt)
#pragma unroll
      for (int r = 0; r < 4; ++r) {
        int m = m0 + wrow * 64 + mt * 16 + quad * 4 + r;
        int col = n0 + wcol * 64 + nt * 16 + l15;
        size_t oidx = (size_t)m * DM + col;
        if (f) ((bf16_t*)out)[oidx] = __float2bfloat16(acc[mt][nt][r]);
        else   ((float*)out)[oidx] = acc[mt][nt][r];
      }
}

// -- causal flash attention: DUAL-Q per block, 4 waves, LDS-staged K/V^T
// with register prefetch (R12/R16-proven best: ~49us). R17's 8-wave
// parity split was neutral (occupancy gain eaten by 73KB LDS + combine
// overhead) — reverted. Added: s_setprio(1) around MFMA clusters (T5;
// blocks on a CU are unsynchronized so the scheduler has arbitration
// room; measured +4-7% on attn-shaped kernels).
__global__ __launch_bounds__(256) void attn_fwd(const bf16_t* __restrict__ Q,
                                                const bf16_t* __restrict__ K,
                                                const bf16_t* __restrict__ VT,
                                                bf16_t* __restrict__ O) {
  int x = blockIdx.x, bh = blockIdx.y;
  int b = bh >> 4, h = bh & 15;
  int g = x + (bh << 4);                    // linear block id (gridDim.x=16)
  int raw = (g + (g >> 8)) & 15;
  const int pmap[16] = {0, 15, 1, 13, 2, 12, 3, 11, 4, 10, 5, 9, 6, 8, 7, 14};
  int p = pmap[raw];
  int qA = p, qB = 31 - p;                  // qA<16<=qB
  int t = threadIdx.x;
  int w = t >> 6, lane = t & 63, l15 = lane & 15, quad = lane >> 4;
  const size_t base = (size_t)bh * SEQ * DK;
  const bf16_t* Qp = Q + base;
  const bf16_t* Kp = K + base;
  const bf16_t* VTp = VT + base;            // [DK][SEQ]

  __shared__ __align__(16) bf16_t Ks[64][72];        // K tile   [k][d]
  __shared__ __align__(16) bf16_t Vs[64][72];        // V^T tile [d][k]
  __shared__ __align__(16) bf16_t Pb[4][2][16][72];  // per-wave P; 0=A 1=B

  int rowA = qA * 64 + w * 16 + l15;
  int rowB = qB * 64 + w * 16 + l15;
  short8 qfA0 = *(const short8*)(Qp + (size_t)rowA * DK + quad * 8);
  short8 qfA1 = *(const short8*)(Qp + (size_t)rowA * DK + 32 + quad * 8);
  short8 qfB0 = *(const short8*)(Qp + (size_t)rowB * DK + quad * 8);
  short8 qfB1 = *(const short8*)(Qp + (size_t)rowB * DK + 32 + quad * 8);

  int srow = t >> 2, scoff = (t & 3) * 16;           // staging layout
  const bf16_t* kst = Kp + (size_t)srow * DK + scoff;
  const bf16_t* vst = VTp + (size_t)srow * SEQ + scoff;

  short8 kA = *(const short8*)(kst);
  short8 kB = *(const short8*)(kst + 8);
  short8 vA = *(const short8*)(vst);
  short8 vB = *(const short8*)(vst + 8);

  f32x4 oA[4] = {}, oB[4] = {};
  float rA[4] = {0.f, 0.f, 0.f, 0.f}, rB[4] = {0.f, 0.f, 0.f, 0.f};

  for (int kb = 0; kb <= qB; ++kb) {
    __syncthreads();
    *(short8*)&Ks[srow][scoff] = kA;
    *(short8*)&Ks[srow][scoff + 8] = kB;
    *(short8*)&Vs[srow][scoff] = vA;
    *(short8*)&Vs[srow][scoff + 8] = vB;
    __syncthreads();

    int nkb = (kb < qB) ? (kb + 1) : qB;
    kA = *(const short8*)(kst + (size_t)nkb * 64 * DK);
    kB = *(const short8*)(kst + (size_t)nkb * 64 * DK + 8);
    vA = *(const short8*)(vst + (size_t)nkb * 64);
    vB = *(const short8*)(vst + (size_t)nkb * 64 + 8);

    bool doA = (kb <= qA);

    // ---- B: QK^T -> softmax-partial -> PV ----
    {
      f32x4 sc[4];
      __builtin_amdgcn_s_setprio(1);
#pragma unroll
      for (int kt = 0; kt < 4; ++kt) {
        f32x4 a = {};
        a = mfma16x16x32(qfB0, *(const short8*)&Ks[kt * 16 + l15][quad * 8], a);
        a = mfma16x16x32(qfB1, *(const short8*)&Ks[kt * 16 + l15][32 + quad * 8], a);
        sc[kt] = a;
      }
      __builtin_amdgcn_s_setprio(0);
      bool diag = (kb == qB);
#pragma unroll
      for (int kt = 0; kt < 4; ++kt)
#pragma unroll
        for (int reg = 0; reg < 4; ++reg) {
          float sv = sc[kt][reg] * 0.125f;
          if (diag) {
            int kg = kt * 16 + l15, qg = w * 16 + quad * 4 + reg;
            if (kg > qg) sv = -30000.0f;   // exp underflows to exactly 0
          }
          float pp = __expf(sv);
          rB[reg] += pp;
          Pb[w][1][quad * 4 + reg][kt * 16 + l15] = __float2bfloat16(pp);
        }
      short8 p0 = *(const short8*)&Pb[w][1][l15][quad * 8];
      short8 p1 = *(const short8*)&Pb[w][1][l15][32 + quad * 8];
      __builtin_amdgcn_s_setprio(1);
#pragma unroll
      for (int dt = 0; dt < 4; ++dt) {
        oB[dt] = mfma16x16x32(p0, *(const short8*)&Vs[dt * 16 + l15][quad * 8], oB[dt]);
        oB[dt] = mfma16x16x32(p1, *(const short8*)&Vs[dt * 16 + l15][32 + quad * 8], oB[dt]);
      }
      __builtin_amdgcn_s_setprio(0);
    }
    // ---- A (only while kb <= qA; wave-uniform branch) ----
    if (doA) {
      f32x4 sc[4];
      __builtin_amdgcn_s_setprio(1);
#pragma unroll
      for (int kt = 0; kt < 4; ++kt) {
        f32x4 a = {};
        a = mfma16x16x32(qfA0, *(const short8*)&Ks[kt * 16 + l15][quad * 8], a);
        a = mfma16x16x32(qfA1, *(const short8*)&Ks[kt * 16 + l15][32 + quad * 8], a);
        sc[kt] = a;
      }
      __builtin_amdgcn_s_setprio(0);
      bool diag = (kb == qA);
#pragma unroll
      for (int kt = 0; kt < 4; ++kt)
#pragma unroll
        for (int reg = 0; reg < 4; ++reg) {
          float sv = sc[kt][reg] * 0.125f;
          if (diag) {
            int kg = kt * 16 + l15, qg = w * 16 + quad * 4 + reg;
            if (kg > qg) sv = -30000.0f;
          }
          float pp = __expf(sv);
          rA[reg] += pp;
          Pb[w][0][quad * 4 + reg][kt * 16 + l15] = __float2bfloat16(pp);
        }
      short8 p0 = *(const short8*)&Pb[w][0][l15][quad * 8];
      short8 p1 = *(const short8*)&Pb[w][0][l15][32 + quad * 8];
      __builtin_amdgcn_s_setprio(1);
#pragma unroll
      for (int dt = 0; dt < 4; ++dt) {
        oA[dt] = mfma16x16x32(p0, *(const short8*)&Vs[dt * 16 + l15][quad * 8], oA[dt]);
        oA[dt] = mfma16x16x32(p1, *(const short8*)&Vs[dt * 16 + l15][32 + quad * 8], oA[dt]);
      }
      __builtin_amdgcn_s_setprio(0);
    }
  }

  // deferred row-sum reduce across the 16-lane groups
  for (int d = 1; d < 16; d <<= 1)
#pragma unroll
    for (int reg = 0; reg < 4; ++reg) {
      rA[reg] += __shfl_xor(rA[reg], d, 64);
      rB[reg] += __shfl_xor(rB[reg], d, 64);
    }

#pragma unroll
  for (int dt = 0; dt < 4; ++dt)
#pragma unroll
    for (int reg = 0; reg < 4; ++reg) {
      int col = h * DK + dt * 16 + l15;
      int qa = qA * 64 + w * 16 + quad * 4 + reg;
      int qb_ = qB * 64 + w * 16 + quad * 4 + reg;
      O[((size_t)b * SEQ + qa) * DM + col] = __float2bfloat16(oA[dt][reg] / rA[reg]);
      O[((size_t)b * SEQ + qb_) * DM + col] = __float2bfloat16(oB[dt][reg] / rB[reg]);
    }
}

extern "C" void kernel_launch(void* const* d_in, const int* in_sizes, int n_in,
                              void* d_out, int out_size, void* d_ws, size_t ws_size,
                              hipStream_t stream) {
  const void* x = d_in[0];
  const int* tokpos = (const int*)d_in[1];
  const void* WQ = d_in[2];
  const void* WK = d_in[3];
  const void* WV = d_in[4];
  const void* WO = d_in[5];

  char* ws = (char*)d_ws;
  const size_t MB = 1024 * 1024;
  bf16_t* WT  = (bf16_t*)ws;              // 0-8 MB: slot0=WO, slots1-3=WQ,WK,WV
  bf16_t* Xc  = (bf16_t*)(ws + 8 * MB);   // 8-16: x bf16 (dead after gemm_qkv)
  bf16_t* Qb  = (bf16_t*)(ws + 16 * MB);  // 16-24: Q roped [b,h,s,d]
  bf16_t* Kb  = (bf16_t*)(ws + 24 * MB);  // 24-32: K roped [b,h,s,d]
  bf16_t* VTb = (bf16_t*)(ws + 32 * MB);  // 32-40: V^T [b,h,d,s]
  bf16_t* Ab  = (bf16_t*)(ws + 8 * MB);   // overlays dead Xc after gemm_qkv
  int* flag   = (int*)(ws + 40 * MB);
  float2* rtab = (float2*)(ws + 41 * MB); // 41-42: rope cos/sin table (1MB)

  dim3 blk(256);
  prep<<<5632, blk, 0, stream>>>(x, Xc, WQ, WK, WV, WO, WT, tokpos, rtab, flag);
  gemm128_qkv<<<dim3(24, 32), blk, 0, stream>>>(Xc, WT + (size_t)DM * DM, Qb, Kb, VTb, rtab);
  attn_fwd<<<dim3(16, 32), blk, 0, stream>>>(Qb, Kb, VTb, Ab);
  gemm128_out<<<dim3(8, 32), blk, 0, stream>>>(Ab, WT, d_out, flag);
}

// Round 19
// 182.719 us; speedup vs baseline: 1.0351x; 1.0193x over previous
//
#include <hip/hip_runtime.h>
#include <hip/hip_bf16.h>

typedef __attribute__((ext_vector_type(8))) short short8;
typedef __attribute__((ext_vector_type(4))) float f32x4;
typedef __hip_bfloat16 bf16_t;

#define SEQ 2048
#define DM 1024
#define NH 16
#define DK 64
#define NKT 16          // K / 64

static __device__ __forceinline__ f32x4 mfma16x16x32(short8 a, short8 b, f32x4 c) {
  return __builtin_amdgcn_mfma_f32_16x16x32_bf16(a, b, c, 0, 0, 0);
}

// ---- async global->LDS DMA, 16B/lane. LDS dest = wave-uniform base +
// lane*16 (hardware-fixed). Global src is per-lane.
typedef const __attribute__((address_space(1))) unsigned int ga_u32_t;
typedef __attribute__((address_space(3))) unsigned int lds_u32_t;
static __device__ __forceinline__ void gld16(const bf16_t* g, bf16_t* l) {
  __builtin_amdgcn_global_load_lds((ga_u32_t*)g, (lds_u32_t*)l, 16, 0, 0);
}
// raw barrier WITHOUT the vmcnt(0) drain __syncthreads inserts.
static __device__ __forceinline__ void bar() { asm volatile("s_barrier" ::: "memory"); }
static __device__ __forceinline__ void wait_vm8() { asm volatile("s_waitcnt vmcnt(8)" ::: "memory"); }
static __device__ __forceinline__ void wait_vm0() { asm volatile("s_waitcnt vmcnt(0)" ::: "memory"); }

// stage one 128x64 A-tile + 128x64 B-tile into bufbase (A at 0, B at 16KB).
// LDS linear; XOR swizzle lives in the SOURCE column (scg, folded into
// asrc/bsrc) and is inverted on frag reads (rule #21; R14: conflicts 20x down).
static __device__ __forceinline__ void stage_tile(const bf16_t* asrc, const bf16_t* bsrc,
                                                  char* bufbase, int w, int kk) {
#pragma unroll
  for (int j = 0; j < 4; ++j) {
    gld16(asrc + (size_t)(j * 32) * DM + kk, (bf16_t*)(bufbase + j * 4096 + w * 1024));
    gld16(bsrc + (size_t)(j * 32) * DM + kk, (bf16_t*)(bufbase + 16384 + j * 4096 + w * 1024));
  }
}

// ---- merged prep: per-block dtype sniff | convert_x (0..4095) |
// transpose_w (4096..5119) | rope table (5120..5631). (R18-proven)
__global__ __launch_bounds__(256) void prep(const void* __restrict__ x,
                                            bf16_t* __restrict__ Xc,
                                            const void* __restrict__ w0,
                                            const void* __restrict__ w1,
                                            const void* __restrict__ w2,
                                            const void* __restrict__ w3,
                                            bf16_t* __restrict__ wt_base,
                                            const int* __restrict__ tokpos,
                                            float2* __restrict__ rtab,
                                            int* __restrict__ flag) {
  __shared__ int flg;
  __shared__ bf16_t tile[64][65];
  int bx = blockIdx.x, t = threadIdx.x;
  if (t < 64) {
    int lane = t;
    int cnt = 0;
    for (int r = 0; r < 4; ++r) {
      unsigned int v = ((const unsigned int*)x)[lane + r * 64];
      int e = (v >> 7) & 0xFF;
      if (e >= 100 && e <= 145) cnt++;
    }
    for (int d = 1; d < 64; d <<= 1) cnt += __shfl_xor(cnt, d, 64);
    if (lane == 0) flg = (cnt >= 192) ? 1 : 0;
  }
  __syncthreads();
  int f = flg;
  if (bx == 0 && t == 0) *flag = f;    // for gemm128_out's output dtype
  if (bx < 4096) {
    int i = bx * 256 + t;
    if (f) {
      ((uint2*)Xc)[i] = ((const uint2*)x)[i];
    } else {
      const float4 v = ((const float4*)x)[i];
      bf16_t o[4] = {__float2bfloat16(v.x), __float2bfloat16(v.y),
                     __float2bfloat16(v.z), __float2bfloat16(v.w)};
      ((uint2*)Xc)[i] = *(const uint2*)o;
    }
  } else if (bx < 5120) {
    int rem = bx - 4096;
    int z = rem >> 8, bxx = rem & 15, byy = (rem >> 4) & 15;
    const void* src = (z == 0) ? w0 : (z == 1) ? w1 : (z == 2) ? w2 : w3;
    bf16_t* dst = wt_base + (size_t)((z + 1) & 3) * DM * DM;
    int tx = t & 63, ty = t >> 6;
    int r0 = byy * 64, c0 = bxx * 64;
    for (int i = 0; i < 64; i += 4) {
      size_t idx = (size_t)(r0 + ty + i) * DM + c0 + tx;
      tile[ty + i][tx] = f ? ((const bf16_t*)src)[idx]
                           : __float2bfloat16(((const float*)src)[idx]);
    }
    __syncthreads();
    for (int i = 0; i < 64; i += 4)
      dst[(size_t)(c0 + ty + i) * DM + r0 + tx] = tile[tx][ty + i];
  } else {
    int i = (bx - 5120) * 256 + t;    // i = m*32 + p
    int m = i >> 5, pp = i & 31;
    float pos = (float)tokpos[m];
    float invf = __powf(10000.0f, -(float)pp * (1.0f / 32.0f));
    float sn, cs;
    sincosf(pos * invf, &sn, &cs);
    rtab[i] = make_float2(cs, sn);
  }
}

// ------ fused QKV GEMM + RoPE(table), 128x128, 2-buf counted-vmcnt --------
// (R16-proven: structure unchanged)
__global__ __launch_bounds__(256) void gemm128_qkv(const bf16_t* __restrict__ A,
                                                   const bf16_t* __restrict__ WTqkv,
                                                   bf16_t* __restrict__ Qb,
                                                   bf16_t* __restrict__ Kb,
                                                   bf16_t* __restrict__ VTo,
                                                   const float2* __restrict__ rtab) {
  __shared__ __align__(16) char smem[65536];        // 2 x 32KB buffers
  int t = threadIdx.x;
  int w = t >> 6, lane = t & 63, l15 = lane & 15, quad = lane >> 4;
  int wrow = w >> 1, wcol = w & 1;
  int m0 = blockIdx.y * 128, nx = blockIdx.x, n0 = nx * 128;
  int srow0 = w * 8 + (lane >> 3);
  int scg = (lane & 7) ^ (lane >> 3);
  const bf16_t* asrc = A + (size_t)(m0 + srow0) * DM + scg * 8;
  const bf16_t* bsrc = WTqkv + (size_t)(n0 + srow0) * DM + scg * 8;

  f32x4 acc[4][4] = {};
  stage_tile(asrc, bsrc, smem, w, 0);
  stage_tile(asrc, bsrc, smem + 32768, w, 64);
  for (int kt = 0; kt < NKT; ++kt) {
    if (kt < NKT - 1) wait_vm8(); else wait_vm0();
    bar();
    const bf16_t* Ab = (const bf16_t*)(smem + (kt & 1) * 32768);
    const bf16_t* Bb = Ab + 8192;
    short8 af[4][2], bfr[4][2];
#pragma unroll
    for (int mt = 0; mt < 4; ++mt) {
      int r = wrow * 64 + mt * 16 + l15;
      af[mt][0] = *(const short8*)(Ab + r * 64 + ((quad ^ (l15 & 7)) * 8));
      af[mt][1] = *(const short8*)(Ab + r * 64 + (((4 + quad) ^ (l15 & 7)) * 8));
    }
#pragma unroll
    for (int nt = 0; nt < 4; ++nt) {
      int r = wcol * 64 + nt * 16 + l15;
      bfr[nt][0] = *(const short8*)(Bb + r * 64 + ((quad ^ (l15 & 7)) * 8));
      bfr[nt][1] = *(const short8*)(Bb + r * 64 + (((4 + quad) ^ (l15 & 7)) * 8));
    }
#pragma unroll
    for (int mt = 0; mt < 4; ++mt)
#pragma unroll
      for (int nt = 0; nt < 4; ++nt) {
        acc[mt][nt] = mfma16x16x32(af[mt][0], bfr[nt][0], acc[mt][nt]);
        acc[mt][nt] = mfma16x16x32(af[mt][1], bfr[nt][1], acc[mt][nt]);
      }
    bar();                                           // reads of buf[kt&1] done
    if (kt + 2 < NKT)
      stage_tile(asrc, bsrc, smem + (kt & 1) * 32768, w, (kt + 2) * 64);
  }

  int sel = nx >> 3;                 // 0=Q, 1=K, 2=V
  int nc = (nx & 7) * 128;
  __syncthreads();                   // buffers dead; carve Tw
  bf16_t (*Tw)[72] = (bf16_t(*)[72])(smem + w * 9216);  // per-wave 64x72
  int b = m0 >> 11;
  int h = (nc >> 6) + wcol;
  if (sel < 2) {
    bf16_t* dst = sel ? Kb : Qb;
    float sgnv = (l15 & 1) ? 1.0f : -1.0f;
#pragma unroll
    for (int mt = 0; mt < 4; ++mt)
#pragma unroll
      for (int r = 0; r < 4; ++r) {
        int m = m0 + wrow * 64 + mt * 16 + quad * 4 + r;
        const float2* tr = rtab + m * 32;
#pragma unroll
        for (int nt = 0; nt < 4; ++nt) {
          int d = nt * 16 + l15;
          float val = acc[mt][nt][r];
          float partner = __shfl_xor(val, 1, 64);
          float2 cssn = tr[d >> 1];
          Tw[mt * 16 + quad * 4 + r][d] = __float2bfloat16(val * cssn.x + sgnv * partner * cssn.y);
        }
      }
    int s_base = (m0 & (SEQ - 1)) + wrow * 64;
    bf16_t* dq = dst + ((size_t)(b * NH + h) * SEQ + s_base) * DK;
#pragma unroll
    for (int c = 0; c < 8; ++c) {
      int row = c * 8 + (lane >> 3);
      int col = (lane & 7) * 8;
      *(short8*)&dq[(size_t)row * DK + col] = *(const short8*)&Tw[row][col];
    }
  } else {
#pragma unroll
    for (int mt = 0; mt < 4; ++mt)
#pragma unroll
      for (int nt = 0; nt < 4; ++nt)
#pragma unroll
        for (int r = 0; r < 4; ++r)
          Tw[nt * 16 + l15][mt * 16 + quad * 4 + r] = __float2bfloat16(acc[mt][nt][r]);
    int s_base = m0 & (SEQ - 1);
#pragma unroll
    for (int c = 0; c < 4; ++c) {
      int d = c * 16 + (lane >> 2);
      int s2 = (lane & 3) * 16;
      size_t ob = ((size_t)(b * NH + h) * DK + d) * SEQ + s_base + wrow * 64 + s2;
      *(short8*)&VTo[ob] = *(const short8*)&Tw[d][s2];
      *(short8*)&VTo[ob + 8] = *(const short8*)&Tw[d][s2 + 8];
    }
  }
}

// ------ out-proj GEMM, same 2-buf counted-vmcnt pipeline (R16-proven) ------
__global__ __launch_bounds__(256) void gemm128_out(const bf16_t* __restrict__ A,
                                                   const bf16_t* __restrict__ BT,
                                                   void* __restrict__ out,
                                                   const int* __restrict__ flag) {
  __shared__ __align__(16) char smem[65536];
  int f = *flag;
  int t = threadIdx.x;
  int w = t >> 6, lane = t & 63, l15 = lane & 15, quad = lane >> 4;
  int wrow = w >> 1, wcol = w & 1;
  int m0 = blockIdx.y * 128, n0 = blockIdx.x * 128;
  int srow0 = w * 8 + (lane >> 3);
  int scg = (lane & 7) ^ (lane >> 3);
  const bf16_t* asrc = A + (size_t)(m0 + srow0) * DM + scg * 8;
  const bf16_t* bsrc = BT + (size_t)(n0 + srow0) * DM + scg * 8;

  f32x4 acc[4][4] = {};
  stage_tile(asrc, bsrc, smem, w, 0);
  stage_tile(asrc, bsrc, smem + 32768, w, 64);
  for (int kt = 0; kt < NKT; ++kt) {
    if (kt < NKT - 1) wait_vm8(); else wait_vm0();
    bar();
    const bf16_t* Ab = (const bf16_t*)(smem + (kt & 1) * 32768);
    const bf16_t* Bb = Ab + 8192;
    short8 af[4][2], bfr[4][2];
#pragma unroll
    for (int mt = 0; mt < 4; ++mt) {
      int r = wrow * 64 + mt * 16 + l15;
      af[mt][0] = *(const short8*)(Ab + r * 64 + ((quad ^ (l15 & 7)) * 8));
      af[mt][1] = *(const short8*)(Ab + r * 64 + (((4 + quad) ^ (l15 & 7)) * 8));
    }
#pragma unroll
    for (int nt = 0; nt < 4; ++nt) {
      int r = wcol * 64 + nt * 16 + l15;
      bfr[nt][0] = *(const short8*)(Bb + r * 64 + ((quad ^ (l15 & 7)) * 8));
      bfr[nt][1] = *(const short8*)(Bb + r * 64 + (((4 + quad) ^ (l15 & 7)) * 8));
    }
#pragma unroll
    for (int mt = 0; mt < 4; ++mt)
#pragma unroll
      for (int nt = 0; nt < 4; ++nt) {
        acc[mt][nt] = mfma16x16x32(af[mt][0], bfr[nt][0], acc[mt][nt]);
        acc[mt][nt] = mfma16x16x32(af[mt][1], bfr[nt][1], acc[mt][nt]);
      }
    bar();
    if (kt + 2 < NKT)
      stage_tile(asrc, bsrc, smem + (kt & 1) * 32768, w, (kt + 2) * 64);
  }
#pragma unroll
  for (int mt = 0; mt < 4; ++mt)
#pragma unroll
    for (int nt = 0; nt < 4; ++nt)
#pragma unroll
      for (int r = 0; r < 4; ++r) {
        int m = m0 + wrow * 64 + mt * 16 + quad * 4 + r;
        int col = n0 + wcol * 64 + nt * 16 + l15;
        size_t oidx = (size_t)m * DM + col;
        if (f) ((bf16_t*)out)[oidx] = __float2bfloat16(acc[mt][nt][r]);
        else   ((float*)out)[oidx] = acc[mt][nt][r];
      }
}

// -- causal flash attention: DUAL-Q per block, 4 waves, LDS-staged K/V^T.
// NEW: Ks/Vs are linear [64][64] with the gemm-proven XOR-granule swizzle
// (write granule g of row r at col (g^(r&7))*8; frag reads invert it).
// R18 counters: the padded-[72] frag reads cost 4.87M conflict cycles
// (~8us/dispatch) — same read shape in the swizzled GEMMs costs 164K.
// setprio removed (R18: neutral-negative on this barrier-synced loop).
__global__ __launch_bounds__(256) void attn_fwd(const bf16_t* __restrict__ Q,
                                                const bf16_t* __restrict__ K,
                                                const bf16_t* __restrict__ VT,
                                                bf16_t* __restrict__ O) {
  int x = blockIdx.x, bh = blockIdx.y;
  int b = bh >> 4, h = bh & 15;
  int g = x + (bh << 4);                    // linear block id (gridDim.x=16)
  int raw = (g + (g >> 8)) & 15;
  const int pmap[16] = {0, 15, 1, 13, 2, 12, 3, 11, 4, 10, 5, 9, 6, 8, 7, 14};
  int p = pmap[raw];
  int qA = p, qB = 31 - p;                  // qA<16<=qB
  int t = threadIdx.x;
  int w = t >> 6, lane = t & 63, l15 = lane & 15, quad = lane >> 4;
  const size_t base = (size_t)bh * SEQ * DK;
  const bf16_t* Qp = Q + base;
  const bf16_t* Kp = K + base;
  const bf16_t* VTp = VT + base;            // [DK][SEQ]

  __shared__ __align__(16) bf16_t Ks[64][64];        // K tile   [k][d] swizzled
  __shared__ __align__(16) bf16_t Vs[64][64];        // V^T tile [d][k] swizzled
  __shared__ __align__(16) bf16_t Pb[4][2][16][72];  // per-wave P; 0=A 1=B

  int rowA = qA * 64 + w * 16 + l15;
  int rowB = qB * 64 + w * 16 + l15;
  short8 qfA0 = *(const short8*)(Qp + (size_t)rowA * DK + quad * 8);
  short8 qfA1 = *(const short8*)(Qp + (size_t)rowA * DK + 32 + quad * 8);
  short8 qfB0 = *(const short8*)(Qp + (size_t)rowB * DK + quad * 8);
  short8 qfB1 = *(const short8*)(Qp + (size_t)rowB * DK + 32 + quad * 8);

  int srow = t >> 2;                         // staging row 0..63
  int g0 = (t & 3) * 2, g1 = g0 + 1;         // source granules (8 elems each)
  int sw = srow & 7;
  int c0 = (g0 ^ sw) * 8, c1 = (g1 ^ sw) * 8;  // swizzled LDS columns
  const bf16_t* kst = Kp + (size_t)srow * DK + g0 * 8;
  const bf16_t* vst = VTp + (size_t)srow * SEQ + g0 * 8;

  short8 kA = *(const short8*)(kst);
  short8 kB = *(const short8*)(kst + 8);
  short8 vA = *(const short8*)(vst);
  short8 vB = *(const short8*)(vst + 8);

  f32x4 oA[4] = {}, oB[4] = {};
  float rA[4] = {0.f, 0.f, 0.f, 0.f}, rB[4] = {0.f, 0.f, 0.f, 0.f};

  for (int kb = 0; kb <= qB; ++kb) {
    __syncthreads();
    *(short8*)&Ks[srow][c0] = kA;
    *(short8*)&Ks[srow][c1] = kB;
    *(short8*)&Vs[srow][c0] = vA;
    *(short8*)&Vs[srow][c1] = vB;
    __syncthreads();

    int nkb = (kb < qB) ? (kb + 1) : qB;
    kA = *(const short8*)(kst + (size_t)nkb * 64 * DK);
    kB = *(const short8*)(kst + (size_t)nkb * 64 * DK + 8);
    vA = *(const short8*)(vst + (size_t)nkb * 64);
    vB = *(const short8*)(vst + (size_t)nkb * 64 + 8);

    bool doA = (kb <= qA);

    // ---- B: QK^T -> softmax-partial -> PV ----
    {
      f32x4 sc[4];
#pragma unroll
      for (int kt = 0; kt < 4; ++kt) {
        int r = kt * 16 + l15, rw = r & 7;
        f32x4 a = {};
        a = mfma16x16x32(qfB0, *(const short8*)&Ks[r][(quad ^ rw) * 8], a);
        a = mfma16x16x32(qfB1, *(const short8*)&Ks[r][((4 + quad) ^ rw) * 8], a);
        sc[kt] = a;
      }
      bool diag = (kb == qB);
#pragma unroll
      for (int kt = 0; kt < 4; ++kt)
#pragma unroll
        for (int reg = 0; reg < 4; ++reg) {
          float sv = sc[kt][reg] * 0.125f;
          if (diag) {
            int kg = kt * 16 + l15, qg = w * 16 + quad * 4 + reg;
            if (kg > qg) sv = -30000.0f;   // exp underflows to exactly 0
          }
          float pp = __expf(sv);
          rB[reg] += pp;
          Pb[w][1][quad * 4 + reg][kt * 16 + l15] = __float2bfloat16(pp);
        }
      short8 p0 = *(const short8*)&Pb[w][1][l15][quad * 8];
      short8 p1 = *(const short8*)&Pb[w][1][l15][32 + quad * 8];
#pragma unroll
      for (int dt = 0; dt < 4; ++dt) {
        int r = dt * 16 + l15, rw = r & 7;
        oB[dt] = mfma16x16x32(p0, *(const short8*)&Vs[r][(quad ^ rw) * 8], oB[dt]);
        oB[dt] = mfma16x16x32(p1, *(const short8*)&Vs[r][((4 + quad) ^ rw) * 8], oB[dt]);
      }
    }
    // ---- A (only while kb <= qA; wave-uniform branch) ----
    if (doA) {
      f32x4 sc[4];
#pragma unroll
      for (int kt = 0; kt < 4; ++kt) {
        int r = kt * 16 + l15, rw = r & 7;
        f32x4 a = {};
        a = mfma16x16x32(qfA0, *(const short8*)&Ks[r][(quad ^ rw) * 8], a);
        a = mfma16x16x32(qfA1, *(const short8*)&Ks[r][((4 + quad) ^ rw) * 8], a);
        sc[kt] = a;
      }
      bool diag = (kb == qA);
#pragma unroll
      for (int kt = 0; kt < 4; ++kt)
#pragma unroll
        for (int reg = 0; reg < 4; ++reg) {
          float sv = sc[kt][reg] * 0.125f;
          if (diag) {
            int kg = kt * 16 + l15, qg = w * 16 + quad * 4 + reg;
            if (kg > qg) sv = -30000.0f;
          }
          float pp = __expf(sv);
          rA[reg] += pp;
          Pb[w][0][quad * 4 + reg][kt * 16 + l15] = __float2bfloat16(pp);
        }
      short8 p0 = *(const short8*)&Pb[w][0][l15][quad * 8];
      short8 p1 = *(const short8*)&Pb[w][0][l15][32 + quad * 8];
#pragma unroll
      for (int dt = 0; dt < 4; ++dt) {
        int r = dt * 16 + l15, rw = r & 7;
        oA[dt] = mfma16x16x32(p0, *(const short8*)&Vs[r][(quad ^ rw) * 8], oA[dt]);
        oA[dt] = mfma16x16x32(p1, *(const short8*)&Vs[r][((4 + quad) ^ rw) * 8], oA[dt]);
      }
    }
  }

  // deferred row-sum reduce across the 16-lane groups
  for (int d = 1; d < 16; d <<= 1)
#pragma unroll
    for (int reg = 0; reg < 4; ++reg) {
      rA[reg] += __shfl_xor(rA[reg], d, 64);
      rB[reg] += __shfl_xor(rB[reg], d, 64);
    }

#pragma unroll
  for (int dt = 0; dt < 4; ++dt)
#pragma unroll
    for (int reg = 0; reg < 4; ++reg) {
      int col = h * DK + dt * 16 + l15;
      int qa = qA * 64 + w * 16 + quad * 4 + reg;
      int qb_ = qB * 64 + w * 16 + quad * 4 + reg;
      O[((size_t)b * SEQ + qa) * DM + col] = __float2bfloat16(oA[dt][reg] / rA[reg]);
      O[((size_t)b * SEQ + qb_) * DM + col] = __float2bfloat16(oB[dt][reg] / rB[reg]);
    }
}

extern "C" void kernel_launch(void* const* d_in, const int* in_sizes, int n_in,
                              void* d_out, int out_size, void* d_ws, size_t ws_size,
                              hipStream_t stream) {
  const void* x = d_in[0];
  const int* tokpos = (const int*)d_in[1];
  const void* WQ = d_in[2];
  const void* WK = d_in[3];
  const void* WV = d_in[4];
  const void* WO = d_in[5];

  char* ws = (char*)d_ws;
  const size_t MB = 1024 * 1024;
  bf16_t* WT  = (bf16_t*)ws;              // 0-8 MB: slot0=WO, slots1-3=WQ,WK,WV
  bf16_t* Xc  = (bf16_t*)(ws + 8 * MB);   // 8-16: x bf16 (dead after gemm_qkv)
  bf16_t* Qb  = (bf16_t*)(ws + 16 * MB);  // 16-24: Q roped [b,h,s,d]
  bf16_t* Kb  = (bf16_t*)(ws + 24 * MB);  // 24-32: K roped [b,h,s,d]
  bf16_t* VTb = (bf16_t*)(ws + 32 * MB);  // 32-40: V^T [b,h,d,s]
  bf16_t* Ab  = (bf16_t*)(ws + 8 * MB);   // overlays dead Xc after gemm_qkv
  int* flag   = (int*)(ws + 40 * MB);
  float2* rtab = (float2*)(ws + 41 * MB); // 41-42: rope cos/sin table (1MB)

  dim3 blk(256);
  prep<<<5632, blk, 0, stream>>>(x, Xc, WQ, WK, WV, WO, WT, tokpos, rtab, flag);
  gemm128_qkv<<<dim3(24, 32), blk, 0, stream>>>(Xc, WT + (size_t)DM * DM, Qb, Kb, VTb, rtab);
  attn_fwd<<<dim3(16, 32), blk, 0, stream>>>(Qb, Kb, VTb, Ab);
  gemm128_out<<<dim3(8, 32), blk, 0, stream>>>(Ab, WT, d_out, flag);
}